// Round 7
// baseline (235.391 us; speedup 1.0000x reference)
//
#include <hip/hip_runtime.h>

#define U 128
#define BATCH 2048
#define NL 8
#define NS 8                       /* NS=15 vs 10 bit-identical; contraction <=0.36 -> NS=8 residual <1e-3 */
#define DTc 0.1f
#define TENf 10.0f                 /* DT/EPS */
#define INVC (1.0f/11.0f)          /* 1/(1+DT/EPS) */
#define AFACT (0.01f/11.0f)        /* DT^2 / c */
#define AST 264                    /* A-tile LDS stride (u16) */
#define ZST 132                    /* zh16 row stride (u16): 264B -> 2-bank shift/row */

typedef unsigned short u16;
typedef __attribute__((ext_vector_type(8))) short bf16x8;
typedef __attribute__((ext_vector_type(4))) float f32x4;
#define MFMA16(a,b,c) __builtin_amdgcn_mfma_f32_16x16x32_bf16(a,b,c,0,0,0)

__device__ __forceinline__ float bf2f(u16 h){ return __uint_as_float(((unsigned int)h)<<16); }
__device__ __forceinline__ u16 f2bf(float f){
  unsigned int u = __float_as_uint(f);
  u += 0x7FFFu + ((u >> 16) & 1u);
  return (u16)(u >> 16);
}
__device__ __forceinline__ float fast_tanh(float x){
  float e = __expf(2.0f*x);
  return 1.0f - __fdividef(2.0f, e + 1.0f);
}
__device__ __forceinline__ int detect_md(const u16* x, int* s_bad, int t, int nthr){
  if(t==0) *s_bad = 0;
  __syncthreads();
  int f=0;
  for(int i=t;i<4096;i+=nthr){ float v = bf2f(x[i]); if(!(fabsf(v)<16.0f)) f=1; }
  if(f) atomicOr(s_bad,1);
  __syncthreads();
  return *s_bad ? 0 : 1;   // 1 = bf16 inputs
}

// device-scope barrier across the 64 setup blocks (all co-resident on 256 CUs)
__device__ __forceinline__ void gbar(int* c, int idx){
  __syncthreads();
  if(threadIdx.x==0){
    __threadfence();
    atomicAdd(&c[idx], 1);
    while(atomicAdd(&c[idx], 0) < 64){ __builtin_amdgcn_s_sleep(8); }
    __threadfence();
  }
  __syncthreads();
}

__global__ void zeroK(int* g){ if(threadIdx.x < 8) g[threadIdx.x] = 0; }

// block tile: 16 rows x 128 cols, K=128; A[m][k] (lda), B[n][k] (ldb). 256 thr.
template<typename EPI>
__device__ __forceinline__ void tile16(const u16* __restrict__ A, int lda,
                                       const u16* __restrict__ B, int ldb, EPI epi){
  const int lane = threadIdx.x & 63, w = threadIdx.x >> 6;
  const int ln = lane & 15, lq = lane >> 4;
  const int n0 = 32*w + ln, n1 = n0 + 16;
  bf16x8 af[4], b0[4], b1[4];
  #pragma unroll
  for(int kt=0;kt<4;kt++){
    af[kt] = *(const bf16x8*)&A[ln*lda + kt*32 + lq*8];
    b0[kt] = *(const bf16x8*)&B[n0*ldb + kt*32 + lq*8];
    b1[kt] = *(const bf16x8*)&B[n1*ldb + kt*32 + lq*8];
  }
  f32x4 a0 = {0,0,0,0}, a1 = {0,0,0,0};
  #pragma unroll
  for(int kt=0;kt<4;kt++){ a0 = MFMA16(af[kt], b0[kt], a0); a1 = MFMA16(af[kt], b1[kt], a1); }
  epi(a0, a1, n0, n1);
}

// ---------------- fused setup: 64 blocks, 6 phases, 5 global barriers --------
__global__ __launch_bounds__(256) void setupF(
    const void* __restrict__ xraw, const void* __restrict__ w_in,
    const void* __restrict__ b_in, const void* __restrict__ wb,
    const void* __restrict__ bb, const void* __restrict__ w_out,
    const void* __restrict__ b_out,
    u16* __restrict__ Fb, u16* __restrict__ Fsw,
    u16* __restrict__ Wg, u16* __restrict__ Wtg,
    u16* __restrict__ Pg, u16* __restrict__ winb,
    float* __restrict__ bbD, float* __restrict__ b_in_f,
    float* __restrict__ w_out_f, float* __restrict__ b_out_f,
    int* __restrict__ gctr){
  __shared__ int s_bad;
  const int t = threadIdx.x;
  const int md = detect_md((const u16*)xraw, &s_bad, t, 256);
  const int L = blockIdx.x >> 3, mt = blockIdx.x & 7;
  const int lq = (threadIdx.x & 63) >> 4;

  // phase 0: convert everything
  {
    const int g = blockIdx.x*256 + t, GS = 64*256;
    for(int i=g;i<100352;i+=GS) winb[i] = md ? ((const u16*)w_in)[i] : f2bf(((const float*)w_in)[i]);
    for(int i=g;i<131072;i+=GS){
      u16 h = md ? ((const u16*)wb)[i] : f2bf(((const float*)wb)[i]);
      Wg[i] = h;
      int Li = i>>14, j = i & 16383;
      Wtg[(Li<<14) + (j&127)*U + (j>>7)] = h;
    }
    for(int i=g;i<NL*U;i+=GS) bbD[i] = DTc * (md ? bf2f(((const u16*)bb)[i]) : ((const float*)bb)[i]);
    for(int i=g;i<U;i+=GS)    b_in_f[i]  = md ? bf2f(((const u16*)b_in)[i])  : ((const float*)b_in)[i];
    for(int i=g;i<1280;i+=GS) w_out_f[i] = md ? bf2f(((const u16*)w_out)[i]) : ((const float*)w_out)[i];
    for(int i=g;i<10;i+=GS)   b_out_f[i] = md ? bf2f(((const u16*)b_out)[i]) : ((const float*)b_out)[i];
  }
  gbar(gctr, 0);

  const u16* WtL = Wtg + (L<<14);
  u16* PgL = Pg + (L<<14);
  u16* FbL = Fb + (size_t)L*65536;

  // phase 1: P = AFACT * Wt @ Wt
  tile16(WtL + mt*16*U, U, WtL, U, [&](f32x4 a0, f32x4 a1, int n0, int n1){
    #pragma unroll
    for(int r=0;r<4;r++){
      int row = mt*16 + lq*4 + r;
      PgL[row*U + n0] = f2bf(AFACT*a0[r]);
      PgL[row*U + n1] = f2bf(AFACT*a1[r]);
    }
  });
  gbar(gctr, 1);

  // phase 2: S = INVC(I - P + P@P) -> Fb00
  tile16(PgL + mt*16*U, U, PgL, U, [&](f32x4 a0, f32x4 a1, int n0, int n1){
    #pragma unroll
    for(int r=0;r<4;r++){
      int row = mt*16 + lq*4 + r;
      FbL[row*256 + n0] = f2bf(INVC*(((row==n0)?1.0f:0.0f) - bf2f(PgL[row*U+n0]) + a0[r]));
      FbL[row*256 + n1] = f2bf(INVC*(((row==n1)?1.0f:0.0f) - bf2f(PgL[row*U+n1]) + a1[r]));
    }
  });
  gbar(gctr, 2);

  // phase 3: Q = DT * S @ Wt -> Fb01, Fb10^T
  tile16(FbL + mt*16*256, 256, Wg + (L<<14), U, [&](f32x4 a0, f32x4 a1, int n0, int n1){
    #pragma unroll
    for(int r=0;r<4;r++){
      int row = mt*16 + lq*4 + r;
      u16 q0 = f2bf(DTc*a0[r]), q1 = f2bf(DTc*a1[r]);
      FbL[row*256 + 128 + n0] = q0;
      FbL[row*256 + 128 + n1] = q1;
      FbL[(128+n0)*256 + row] = q0;
      FbL[(128+n1)*256 + row] = q1;
    }
  });
  gbar(gctr, 3);

  // phase 4: R = DT * W @ Q -> Fb11
  tile16(Wg + (L<<14) + mt*16*U, U, FbL + 128*256, 256, [&](f32x4 a0, f32x4 a1, int n0, int n1){
    #pragma unroll
    for(int r=0;r<4;r++){
      int row = mt*16 + lq*4 + r;
      FbL[(128+row)*256 + 128 + n0] = f2bf(DTc*a0[r]);
      FbL[(128+row)*256 + 128 + n1] = f2bf(DTc*a1[r]);
    }
  });
  gbar(gctr, 4);

  // phase 5: swizzle to fragment-major for 16-col wave groups:
  // slot i (per L): lane=i&63, kt=(i>>6)&7, w=(i>>9)&15; n=16w+ln, k=kt*32+lq*8
  for(int i = mt*1024 + t; i < (mt+1)*1024; i += 256){
    int lanei = i & 63, kt = (i>>6)&7, w = (i>>9)&15;
    int lni = lanei & 15, lqi = lanei >> 4;
    *(bf16x8*)&Fsw[((size_t)L*8192 + i)*8] = *(const bf16x8*)&FbL[(16*w+lni)*256 + kt*32 + lqi*8];
  }
}

// ---------------- main: 16 rows/block, 16 waves (4/SIMD), 1 barrier/step -----
__global__ __launch_bounds__(1024) void mainK(
    const void* __restrict__ xraw, const u16* __restrict__ winb,
    const float* __restrict__ b_in_f, const bf16x8* __restrict__ Fsw,
    const float* __restrict__ bbD, const float* __restrict__ w_out_f,
    const float* __restrict__ b_out_f, void* __restrict__ outraw){
  __shared__ u16 At[2][16*AST];          // 16.9 KB ping-pong A tiles [T | r_u]
  __shared__ u16 zh16[NL*16*ZST];        // 33.8 KB z-history u-half
  __shared__ float zinu[16*U];           //  8 KB
  __shared__ float bbL[NL*U];            //  4 KB (DT*b)
  __shared__ float lg[16*12];
  __shared__ int s_bad;
  float* uout = (float*)&At[0][0];

  const int t = threadIdx.x;
  const int lane = t & 63, wid = t >> 6, ln = lane & 15, lq = lane >> 4;
  const int r0 = blockIdx.x * 16;

  const int md = detect_md((const u16*)xraw, &s_bad, t, 1024);
  for(int i=t;i<NL*U;i+=1024) bbL[i] = bbD[i];
  __syncthreads();

  // ---- phase 1: z1 = x @ w_in^T + b_in (waves 0..7, one 16-col frag each) ----
  if(wid < 8){
    const int n0 = 16*wid + ln;
    f32x4 acc = {0,0,0,0};
    for(int kt=0; kt<25; ++kt){
      int k0 = kt*32 + lq*8;
      bf16x8 av = {0,0,0,0,0,0,0,0}, bv = {0,0,0,0,0,0,0,0};
      if(k0 < 784){
        if(md){
          av = *(const bf16x8*)((const u16*)xraw + (size_t)(r0+ln)*784 + k0);
        } else {
          const float* xp = (const float*)xraw + (size_t)(r0+ln)*784 + k0;
          float4 f0 = *(const float4*)xp, f1 = *(const float4*)(xp+4);
          av[0]=(short)f2bf(f0.x); av[1]=(short)f2bf(f0.y); av[2]=(short)f2bf(f0.z); av[3]=(short)f2bf(f0.w);
          av[4]=(short)f2bf(f1.x); av[5]=(short)f2bf(f1.y); av[6]=(short)f2bf(f1.z); av[7]=(short)f2bf(f1.w);
        }
        bv = *(const bf16x8*)&winb[(size_t)n0*784 + k0];
      }
      acc = MFMA16(av, bv, acc);
    }
    #pragma unroll
    for(int r=0;r<4;r++) zinu[(lq*4+r)*U + n0] = acc[r] + b_in_f[n0];
  }
  __syncthreads();

  // ---- init: z-history, A-tile(0), r_u regs ----
  for(int i=t; i<NL*16*U; i+=1024){
    int l = i>>11, row = (i>>7)&15, c = i&127;
    zh16[(l*16+row)*ZST + c] = f2bf(zinu[row*U + c]);
  }
  float ru[4];
  if(wid < 8){
    const int n = 16*wid + ln;
    #pragma unroll
    for(int r=0;r<4;r++){
      int row = lq*4 + r;
      At[0][row*AST + n] = f2bf((TENf + 1.0f) * fast_tanh(zinu[row*U + n]));
    }
  } else {
    const int uc = 16*(wid-8) + ln;
    #pragma unroll
    for(int r=0;r<4;r++){
      int row = lq*4 + r;
      float v = zinu[row*U + uc] + bbL[uc];
      ru[r] = v;
      At[0][row*AST + 128 + uc] = f2bf(v);
    }
  }
  // F fragment base for this wave (coalesced fragment-major; layer stride 8192 slots)
  const bf16x8* fbase = Fsw + wid*512 + lane;
  bf16x8 BfA[8], BfB[8];
  #pragma unroll
  for(int kt=0;kt<8;kt++) BfA[kt] = fbase[kt*64];
  __syncthreads();

#define STEPBODY(STEPV, BC, BN, CURC) { \
    const int l = (STEPV) & 7; \
    const int lnext = (l+1) & 7; \
    const bool last = ((STEPV) == NS*NL-1); \
    { const bf16x8* fp = fbase + lnext*8192; \
      _Pragma("unroll") \
      for(int kt=0;kt<8;kt++) BN[kt] = fp[kt*64]; } \
    bf16x8 at8[8]; \
    _Pragma("unroll") \
    for(int kt=0;kt<8;kt++) at8[kt] = *(const bf16x8*)&At[CURC][ln*AST + kt*32 + lq*8]; \
    float th[4]; \
    if(wid < 8 && !last){ \
      _Pragma("unroll") \
      for(int r=0;r<4;r++) \
        th[r] = TENf * fast_tanh(bf2f(zh16[(lnext*16 + lq*4 + r)*ZST + 16*wid + ln])); \
    } \
    f32x4 acc = {0,0,0,0}; \
    _Pragma("unroll") \
    for(int kt=0;kt<8;kt++) acc = MFMA16(at8[kt], BC[kt], acc); \
    if(wid < 8){ \
      if(!last){ \
        const bool wrap = (l == 7); \
        const int n = 16*wid + ln; \
        _Pragma("unroll") \
        for(int r=0;r<4;r++){ \
          int row = lq*4 + r; \
          float base = wrap ? fast_tanh(zinu[row*U + n]) : acc[r]; \
          At[1-(CURC)][row*AST + n] = f2bf(th[r] + base); \
        } \
      } \
    } else { \
      const int uc = 16*(wid-8) + ln; \
      _Pragma("unroll") \
      for(int r=0;r<4;r++){ \
        int row = lq*4 + r; \
        float yu = ru[r] - acc[r]; \
        zh16[(l*16+row)*ZST + uc] = f2bf(yu); \
        if(last){ \
          uout[row*U + uc] = zinu[row*U + uc] + bbL[7*U + uc] - acc[r]; \
        } else if(l == 7){ \
          float rn = zinu[row*U + uc] + bbL[uc]; \
          ru[r] = rn; \
          At[1-(CURC)][row*AST + 128 + uc] = f2bf(rn); \
        } else { \
          float rn = yu + bbL[(l+1)*U + uc]; \
          ru[r] = rn; \
          At[1-(CURC)][row*AST + 128 + uc] = f2bf(rn); \
        } \
      } \
    } \
    __syncthreads(); \
  }

  for(int sp=0; sp<NS*NL; sp+=2){
    STEPBODY(sp,   BfA, BfB, 0)
    STEPBODY(sp+1, BfB, BfA, 1)
  }
#undef STEPBODY

  // ---- logits + softmax ----
  if(t < 160){
    int mm = t/10, o = t - mm*10;
    float a = b_out_f[o];
    const float* wo = w_out_f + o*U;
    for(int k=0;k<U;k++) a += uout[mm*U + k]*wo[k];
    lg[mm*12 + o] = a;
  }
  __syncthreads();
  if(t < 16){
    float mx = -1e30f;
    for(int o=0;o<10;o++) mx = fmaxf(mx, lg[t*12 + o]);
    float e[10]; float sum = 0.0f;
    for(int o=0;o<10;o++){ e[o] = __expf(lg[t*12 + o] - mx); sum += e[o]; }
    float inv = 1.0f / sum;
    for(int o=0;o<10;o++){
      float pv = e[o]*inv;
      if(md) ((u16*)outraw)[(size_t)(r0 + t)*10 + o] = f2bf(pv);
      else   ((float*)outraw)[(size_t)(r0 + t)*10 + o] = pv;
    }
  }
}

extern "C" void kernel_launch(void* const* d_in, const int* in_sizes, int n_in,
                              void* d_out, int out_size, void* d_ws, size_t ws_size,
                              hipStream_t stream) {
  char* p = (char*)d_ws;
  u16* Fb      = (u16*)p;  p += (size_t)8*256*256*2;   // 1 MB
  u16* Fsw     = (u16*)p;  p += (size_t)8*256*256*2;   // 1 MB
  u16* Wg      = (u16*)p;  p += (size_t)8*128*128*2;   // 256 KB
  u16* Wtg     = (u16*)p;  p += (size_t)8*128*128*2;
  u16* Pg      = (u16*)p;  p += (size_t)8*128*128*2;
  u16* winb    = (u16*)p;  p += 200704;
  float* bbD   = (float*)p; p += 4096;
  float* b_in_f = (float*)p; p += 512;
  float* w_out_f = (float*)p; p += 5120;
  float* b_out_f = (float*)p; p += 64;
  int* gctr    = (int*)p;  p += 64;

  zeroK<<<1, 64, 0, stream>>>(gctr);
  setupF<<<64, 256, 0, stream>>>(d_in[0], d_in[1], d_in[2], d_in[3], d_in[4],
                                 d_in[5], d_in[6],
                                 Fb, Fsw, Wg, Wtg, Pg, winb, bbD, b_in_f,
                                 w_out_f, b_out_f, gctr);
  mainK<<<BATCH/16, 1024, 0, stream>>>(d_in[0], winb, b_in_f, (const bf16x8*)Fsw, bbD,
                                       w_out_f, b_out_f, d_out);
}

// Round 8
// 224.693 us; speedup vs baseline: 1.0476x; 1.0476x over previous
//
#include <hip/hip_runtime.h>

#define U 128
#define BATCH 2048
#define NL 8
#define NS 8                       /* NS=15 vs 10 bit-identical; contraction <=0.36 -> NS=8 residual <1e-3 */
#define DTc 0.1f
#define TENf 10.0f                 /* DT/EPS */
#define INVC (1.0f/11.0f)          /* 1/(1+DT/EPS) */
#define AFACT (0.01f/11.0f)        /* DT^2 / c */
#define AST 264                    /* A-tile LDS stride (u16) */
#define ZST 132                    /* zh16 row stride (u16) */

typedef unsigned short u16;
typedef __attribute__((ext_vector_type(8))) short bf16x8;
typedef __attribute__((ext_vector_type(4))) float f32x4;
#define MFMA16(a,b,c) __builtin_amdgcn_mfma_f32_16x16x32_bf16(a,b,c,0,0,0)

__device__ __forceinline__ float bf2f(u16 h){ return __uint_as_float(((unsigned int)h)<<16); }
__device__ __forceinline__ u16 f2bf(float f){
  unsigned int u = __float_as_uint(f);
  u += 0x7FFFu + ((u >> 16) & 1u);
  return (u16)(u >> 16);
}
__device__ __forceinline__ float fast_tanh(float x){
  float e = __expf(2.0f*x);
  return 1.0f - __fdividef(2.0f, e + 1.0f);
}
__device__ __forceinline__ int detect_md(const u16* x, int* s_bad, int t, int nthr){
  if(t==0) *s_bad = 0;
  __syncthreads();
  int f=0;
  for(int i=t;i<4096;i+=nthr){ float v = bf2f(x[i]); if(!(fabsf(v)<16.0f)) f=1; }
  if(f) atomicOr(s_bad,1);
  __syncthreads();
  return *s_bad ? 0 : 1;   // 1 = bf16 inputs
}

// 1024-thread LDS GEMM tile: 16 waves; wave w: rows (w>>1)*16..+16, cols (w&1)*64..+64.
// A[m][k] (stride U), B stored [n][k] (stride U). out rows rb+r, col n.
template<typename EPI>
__device__ __forceinline__ void tile1024(const u16* A, const u16* B, EPI epi){
  const int t = threadIdx.x, lane = t & 63, w = t >> 6;
  const int ln = lane & 15, lq = lane >> 4;
  const int m0 = (w >> 1) * 16;
  const int nb = (w & 1) * 64;
  bf16x8 af[4];
  #pragma unroll
  for(int kt=0;kt<4;kt++) af[kt] = *(const bf16x8*)&A[(m0+ln)*U + kt*32 + lq*8];
  #pragma unroll
  for(int cf=0;cf<4;cf++){
    int n = nb + cf*16 + ln;
    f32x4 acc = {0,0,0,0};
    #pragma unroll
    for(int kt=0;kt<4;kt++){
      bf16x8 bf = *(const bf16x8*)&B[n*U + kt*32 + lq*8];
      acc = MFMA16(af[kt], bf, acc);
    }
    epi(acc, m0 + lq*4, n);
  }
}

// ---------------- setup: 9 blocks; blocks 0-7 one layer each, all in LDS -----
__global__ __launch_bounds__(1024) void setupF(
    const void* __restrict__ xraw, const void* __restrict__ w_in,
    const void* __restrict__ b_in, const void* __restrict__ wb,
    const void* __restrict__ bb, const void* __restrict__ w_out,
    const void* __restrict__ b_out,
    u16* __restrict__ Fsw, u16* __restrict__ winb,
    float* __restrict__ bbD, float* __restrict__ b_in_f,
    float* __restrict__ w_out_f, float* __restrict__ b_out_f){
  __shared__ u16 arrA[U*U];   // W
  __shared__ u16 arrB[U*U];   // Wt -> S
  __shared__ u16 arrC[U*U];   // P  -> QT
  __shared__ u16 arrD[U*U];   // R
  __shared__ int s_bad;
  const int t = threadIdx.x;
  const int md = detect_md((const u16*)xraw, &s_bad, t, 1024);

  if(blockIdx.x == 8){
    for(int i=t;i<100352;i+=1024) winb[i] = md ? ((const u16*)w_in)[i] : f2bf(((const float*)w_in)[i]);
    for(int i=t;i<NL*U;i+=1024)   bbD[i]  = DTc * (md ? bf2f(((const u16*)bb)[i]) : ((const float*)bb)[i]);
    for(int i=t;i<U;i+=1024)      b_in_f[i]  = md ? bf2f(((const u16*)b_in)[i])  : ((const float*)b_in)[i];
    for(int i=t;i<1280;i+=1024)   w_out_f[i] = md ? bf2f(((const u16*)w_out)[i]) : ((const float*)w_out)[i];
    if(t<10)                      b_out_f[t] = md ? bf2f(((const u16*)b_out)[t]) : ((const float*)b_out)[t];
    return;
  }
  const int L = blockIdx.x;

  // phase 1: convert W -> arrA (W[m][k]) and arrB (Wt[m][k] = W[k][m])
  for(int i=t;i<U*U;i+=1024){
    u16 h = md ? ((const u16*)wb)[(L<<14)+i] : f2bf(((const float*)wb)[(L<<14)+i]);
    arrA[i] = h;
    arrB[(i&127)*U + (i>>7)] = h;
  }
  __syncthreads();

  // phase 2: P = AFACT * Wt @ Wt^T  (P[m][n] = sum_k Wt[m][k] Wt[n][k]) -> arrC
  tile1024(arrB, arrB, [&](f32x4 acc, int rb, int col){
    #pragma unroll
    for(int r=0;r<4;r++) arrC[(rb+r)*U + col] = f2bf(AFACT*acc[r]);
  });
  __syncthreads();

  // phase 3: S = INVC(I - P + P@P) -> arrB (Wt dead)
  tile1024(arrC, arrC, [&](f32x4 acc, int rb, int col){
    #pragma unroll
    for(int r=0;r<4;r++){
      int row = rb + r;
      arrB[row*U + col] = f2bf(INVC*(((row==col)?1.0f:0.0f) - bf2f(arrC[row*U+col]) + acc[r]));
    }
  });
  __syncthreads();

  // phase 4: Q = DT * S @ Wt (Q[m][n] = sum_k S[m][k] W[n][k]); store QT -> arrC (P dead)
  tile1024(arrB, arrA, [&](f32x4 acc, int rb, int col){
    #pragma unroll
    for(int r=0;r<4;r++) arrC[col*U + (rb+r)] = f2bf(DTc*acc[r]);
  });
  __syncthreads();

  // phase 5: R = DT * W @ Q  (R[m][n] = sum_k W[m][k] QT[n][k]) -> arrD
  tile1024(arrA, arrC, [&](f32x4 acc, int rb, int col){
    #pragma unroll
    for(int r=0;r<4;r++) arrD[(rb+r)*U + col] = f2bf(DTc*acc[r]);
  });
  __syncthreads();

  // phase 6: swizzle to fragment-major Fsw. slot i: lane=i&63, kt=(i>>6)&7, w=(i>>9)&15;
  // content = F_B[n=16w+ln][k=kt*32+lq*8+j] = Fmat[k][n]
  for(int i=t;i<8192;i+=1024){
    int lane = i & 63, kt = (i>>6)&7, w = (i>>9)&15;
    int ln = lane & 15, lq = lane >> 4;
    int n = 16*w + ln, k0 = kt*32 + lq*8;
    bf16x8 v;
    if(n < U){
      if(k0 < U){
        v = *(const bf16x8*)&arrB[n*U + k0];                       // S (sym)
      } else {
        #pragma unroll
        for(int j=0;j<8;j++) v[j] = (short)arrC[(k0-U+j)*U + n];   // Q[n][k'] = QT[k'][n]
      }
    } else {
      if(k0 < U) v = *(const bf16x8*)&arrC[(n-U)*U + k0];          // Q[k][n'] = QT[n'][k]
      else       v = *(const bf16x8*)&arrD[(n-U)*U + (k0-U)];      // R (sym)
    }
    *(bf16x8*)&Fsw[((size_t)L*8192 + i)*8] = v;
  }
}

// ---------------- main: 16 rows/block, 16 waves (4/SIMD), 1 barrier/step -----
__global__ __launch_bounds__(1024, 4) void mainK(
    const void* __restrict__ xraw, const u16* __restrict__ winb,
    const float* __restrict__ b_in_f, const bf16x8* __restrict__ Fsw,
    const float* __restrict__ bbD, const float* __restrict__ w_out_f,
    const float* __restrict__ b_out_f, void* __restrict__ outraw){
  __shared__ u16 At[2][16*AST];          // 16.9 KB ping-pong A tiles [T | r_u]
  __shared__ u16 zh16[NL*16*ZST];        // 33.8 KB z-history u-half
  __shared__ float zinu[16*U];           //  8 KB
  __shared__ float bbL[NL*U];            //  4 KB (DT*b)
  __shared__ float lg[16*12];
  __shared__ int s_bad;
  float* uout = (float*)&At[0][0];

  const int t = threadIdx.x;
  const int lane = t & 63, wid = t >> 6, ln = lane & 15, lq = lane >> 4;
  const int r0 = blockIdx.x * 16;

  const int md = detect_md((const u16*)xraw, &s_bad, t, 1024);
  for(int i=t;i<NL*U;i+=1024) bbL[i] = bbD[i];
  __syncthreads();

  // ---- phase 1: z1 = x @ w_in^T + b_in (waves 0..7, one 16-col frag each) ----
  if(wid < 8){
    const int n0 = 16*wid + ln;
    f32x4 acc = {0,0,0,0};
    for(int kt=0; kt<25; ++kt){
      int k0 = kt*32 + lq*8;
      bf16x8 av = {0,0,0,0,0,0,0,0}, bv = {0,0,0,0,0,0,0,0};
      if(k0 < 784){
        if(md){
          av = *(const bf16x8*)((const u16*)xraw + (size_t)(r0+ln)*784 + k0);
        } else {
          const float* xp = (const float*)xraw + (size_t)(r0+ln)*784 + k0;
          float4 f0 = *(const float4*)xp, f1 = *(const float4*)(xp+4);
          av[0]=(short)f2bf(f0.x); av[1]=(short)f2bf(f0.y); av[2]=(short)f2bf(f0.z); av[3]=(short)f2bf(f0.w);
          av[4]=(short)f2bf(f1.x); av[5]=(short)f2bf(f1.y); av[6]=(short)f2bf(f1.z); av[7]=(short)f2bf(f1.w);
        }
        bv = *(const bf16x8*)&winb[(size_t)n0*784 + k0];
      }
      acc = MFMA16(av, bv, acc);
    }
    #pragma unroll
    for(int r=0;r<4;r++) zinu[(lq*4+r)*U + n0] = acc[r] + b_in_f[n0];
  }
  __syncthreads();

  // ---- init: z-history, A-tile(0), r_u regs ----
  for(int i=t; i<NL*16*U; i+=1024){
    int l = i>>11, row = (i>>7)&15, c = i&127;
    zh16[(l*16+row)*ZST + c] = f2bf(zinu[row*U + c]);
  }
  float ru[4];
  if(wid < 8){
    const int n = 16*wid + ln;
    #pragma unroll
    for(int r=0;r<4;r++){
      int row = lq*4 + r;
      At[0][row*AST + n] = f2bf((TENf + 1.0f) * fast_tanh(zinu[row*U + n]));
    }
  } else {
    const int uc = 16*(wid-8) + ln;
    #pragma unroll
    for(int r=0;r<4;r++){
      int row = lq*4 + r;
      float v = zinu[row*U + uc] + bbL[uc];
      ru[r] = v;
      At[0][row*AST + 128 + uc] = f2bf(v);
    }
  }
  // F fragment base for this wave (coalesced fragment-major; layer stride 8192 slots)
  const bf16x8* fbase = Fsw + wid*512 + lane;
  bf16x8 BfA[8], BfB[8];
  #pragma unroll
  for(int kt=0;kt<8;kt++) BfA[kt] = fbase[kt*64];
  __syncthreads();

#define STEPBODY(STEPV, BC, BN, CURC) { \
    const int l = (STEPV) & 7; \
    const int lnext = (l+1) & 7; \
    const bool last = ((STEPV) == NS*NL-1); \
    { const bf16x8* fp = fbase + lnext*8192; \
      _Pragma("unroll") \
      for(int kt=0;kt<8;kt++) BN[kt] = fp[kt*64]; } \
    bf16x8 at8[8]; \
    _Pragma("unroll") \
    for(int kt=0;kt<8;kt++) at8[kt] = *(const bf16x8*)&At[CURC][ln*AST + kt*32 + lq*8]; \
    float th[4]; \
    if(wid < 8 && !last){ \
      _Pragma("unroll") \
      for(int r=0;r<4;r++) \
        th[r] = TENf * fast_tanh(bf2f(zh16[(lnext*16 + lq*4 + r)*ZST + 16*wid + ln])); \
    } \
    f32x4 acc = {0,0,0,0}; \
    _Pragma("unroll") \
    for(int kt=0;kt<8;kt++) acc = MFMA16(at8[kt], BC[kt], acc); \
    if(wid < 8){ \
      if(!last){ \
        const bool wrap = (l == 7); \
        const int n = 16*wid + ln; \
        _Pragma("unroll") \
        for(int r=0;r<4;r++){ \
          int row = lq*4 + r; \
          float base = wrap ? fast_tanh(zinu[row*U + n]) : acc[r]; \
          At[1-(CURC)][row*AST + n] = f2bf(th[r] + base); \
        } \
      } \
    } else { \
      const int uc = 16*(wid-8) + ln; \
      _Pragma("unroll") \
      for(int r=0;r<4;r++){ \
        int row = lq*4 + r; \
        float yu = ru[r] - acc[r]; \
        zh16[(l*16+row)*ZST + uc] = f2bf(yu); \
        if(last){ \
          uout[row*U + uc] = zinu[row*U + uc] + bbL[7*U + uc] - acc[r]; \
        } else if(l == 7){ \
          float rn = zinu[row*U + uc] + bbL[uc]; \
          ru[r] = rn; \
          At[1-(CURC)][row*AST + 128 + uc] = f2bf(rn); \
        } else { \
          float rn = yu + bbL[(l+1)*U + uc]; \
          ru[r] = rn; \
          At[1-(CURC)][row*AST + 128 + uc] = f2bf(rn); \
        } \
      } \
    } \
    __syncthreads(); \
  }

  for(int sp=0; sp<NS*NL; sp+=2){
    STEPBODY(sp,   BfA, BfB, 0)
    STEPBODY(sp+1, BfB, BfA, 1)
  }
#undef STEPBODY

  // ---- logits + softmax ----
  if(t < 160){
    int mm = t/10, o = t - mm*10;
    float a = b_out_f[o];
    const float* wo = w_out_f + o*U;
    for(int k=0;k<U;k++) a += uout[mm*U + k]*wo[k];
    lg[mm*12 + o] = a;
  }
  __syncthreads();
  if(t < 16){
    float mx = -1e30f;
    for(int o=0;o<10;o++) mx = fmaxf(mx, lg[t*12 + o]);
    float e[10]; float sum = 0.0f;
    for(int o=0;o<10;o++){ e[o] = __expf(lg[t*12 + o] - mx); sum += e[o]; }
    float inv = 1.0f / sum;
    for(int o=0;o<10;o++){
      float pv = e[o]*inv;
      if(md) ((u16*)outraw)[(size_t)(r0 + t)*10 + o] = f2bf(pv);
      else   ((float*)outraw)[(size_t)(r0 + t)*10 + o] = pv;
    }
  }
}

extern "C" void kernel_launch(void* const* d_in, const int* in_sizes, int n_in,
                              void* d_out, int out_size, void* d_ws, size_t ws_size,
                              hipStream_t stream) {
  char* p = (char*)d_ws;
  u16* Fsw     = (u16*)p;  p += (size_t)8*256*256*2;   // 1 MB fragment-major F
  u16* winb    = (u16*)p;  p += 200704;
  float* bbD   = (float*)p; p += 4096;
  float* b_in_f = (float*)p; p += 512;
  float* w_out_f = (float*)p; p += 5120;
  float* b_out_f = (float*)p; p += 64;

  setupF<<<9, 1024, 0, stream>>>(d_in[0], d_in[1], d_in[2], d_in[3], d_in[4],
                                 d_in[5], d_in[6],
                                 Fsw, winb, bbD, b_in_f, w_out_f, b_out_f);
  mainK<<<BATCH/16, 1024, 0, stream>>>(d_in[0], winb, b_in_f, (const bf16x8*)Fsw, bbD,
                                       w_out_f, b_out_f, d_out);
}